// Round 16
// baseline (665.920 us; speedup 1.0000x reference)
//
#include <hip/hip_runtime.h>
#include <math.h>

#define LEAKY 0.01f

using short8   = __attribute__((ext_vector_type(8))) short;
using f32x4    = __attribute__((ext_vector_type(4))) float;
using ushort4e = __attribute__((ext_vector_type(4))) unsigned short;

__device__ __forceinline__ ushort f2bf(float f) {
  uint u = __float_as_uint(f);
  uint r = (u + 0x7FFFu + ((u >> 16) & 1u)) >> 16;
  return (ushort)r;
}
__device__ __forceinline__ float bf2f(ushort h) {
  uint u = ((uint)h) << 16;
  return __uint_as_float(u);
}

// ---------------- fused: degree count + x/W -> bf16 prep ----------------

__global__ void k_count_prep(const int* __restrict__ dst, int* __restrict__ cnt, int E,
                             const float* __restrict__ X, ushort* __restrict__ Xb, long xq,
                             const float* __restrict__ W1, ushort* __restrict__ Wt1,
                             int K1, int N1,
                             const float* __restrict__ W2, ushort* __restrict__ Wt2,
                             int K2, int N2) {
  long i = (long)blockIdx.x * blockDim.x + threadIdx.x;
  if (i < E) atomicAdd(&cnt[dst[i]], 1);
  if (i < xq) {
    long b = i * 4;
    float4 v = *reinterpret_cast<const float4*>(&X[b]);
    ushort4e u = {f2bf(v.x), f2bf(v.y), f2bf(v.z), f2bf(v.w)};
    *reinterpret_cast<ushort4e*>(&Xb[b]) = u;
  } else {
    long j = i - xq;
    long t1 = (long)K1 * N1;
    if (j < t1) {
      int k = (int)(j / N1), n = (int)(j % N1);
      Wt1[(long)n * K1 + k] = f2bf(W1[j]);
    } else if (j < t1 + (long)K2 * N2) {
      long jj = j - t1;
      int k = (int)(jj / N2), n = (int)(jj % N2);
      Wt2[(long)n * K2 + k] = f2bf(W2[jj]);
    }
  }
}

// single block, 1024 threads; N <= 16384. Also emits dinv = rsqrt(cnt+1).
__global__ void k_scan(const int* __restrict__ cnt, int* __restrict__ rowstart,
                       int* __restrict__ cursor, float* __restrict__ dinv,
                       int N, int Etot) {
  __shared__ int part[1024];
  const int t = threadIdx.x;
  const int CH = 16;
  int base = t * CH;
  int local[CH];
  int s = 0;
#pragma unroll
  for (int i = 0; i < CH; i++) {
    int v = (base + i < N) ? cnt[base + i] : 0;
    if (base + i < N) dinv[base + i] = rsqrtf((float)v + 1.0f);
    local[i] = s;
    s += v;
  }
  part[t] = s;
  __syncthreads();
  for (int off = 1; off < 1024; off <<= 1) {
    int add = (t >= off) ? part[t - off] : 0;
    __syncthreads();
    part[t] += add;
    __syncthreads();
  }
  int excl = (t == 0) ? 0 : part[t - 1];
#pragma unroll
  for (int i = 0; i < CH; i++) {
    if (base + i < N) {
      int rs = excl + local[i];
      rowstart[base + i] = rs;
      cursor[base + i] = rs;
    }
  }
  if (t == 0) rowstart[N] = Etot;
}

// ---------------- gather aggregation: bf16 in/out, packed edge records ----------------
template <int F, int WAVES, bool LAST>
__global__ __launch_bounds__(64 * WAVES) void k_agg(const ushort* __restrict__ hlin,
                                                    const float* __restrict__ dinv,
                                                    const int* __restrict__ rowstart,
                                                    const unsigned long long* __restrict__ epack,
                                                    const float* __restrict__ bias,
                                                    ushort* __restrict__ aggb,
                                                    float* __restrict__ outh, int N) {
  constexpr int FS = F / WAVES;
  const int node = blockIdx.x;
  const int tid = threadIdx.x;
  const int w = tid >> 6;
  const int lane = tid & 63;
  const int f0 = w * FS + lane * 2;
  const float di = dinv[node];

  float acc0, acc1;
  {
    uint v = *reinterpret_cast<const uint*>(&hlin[(long)node * F + f0]);
    float dd = di * di;
    acc0 = bf2f((ushort)(v & 0xffff)) * dd;
    acc1 = bf2f((ushort)(v >> 16)) * dd;
  }
  const int e0 = rowstart[node], e1 = rowstart[node + 1];
  int e = e0;
  for (; e + 7 < e1; e += 8) {
#pragma unroll
    for (int u = 0; u < 8; u++) {
      unsigned long long pk = epack[e + u];
      int s = (int)(unsigned)(pk & 0xffffffffull);
      float nm = __uint_as_float((uint)(pk >> 32));
      uint v = *reinterpret_cast<const uint*>(&hlin[(long)s * F + f0]);
      acc0 += bf2f((ushort)(v & 0xffff)) * nm;
      acc1 += bf2f((ushort)(v >> 16)) * nm;
    }
  }
  for (; e < e1; e++) {
    unsigned long long pk = epack[e];
    int s = (int)(unsigned)(pk & 0xffffffffull);
    float nm = __uint_as_float((uint)(pk >> 32));
    uint v = *reinterpret_cast<const uint*>(&hlin[(long)s * F + f0]);
    acc0 += bf2f((ushort)(v & 0xffff)) * nm;
    acc1 += bf2f((ushort)(v >> 16)) * nm;
  }

  float v0 = acc0 + bias[f0];
  float v1 = acc1 + bias[f0 + 1];
  v0 = (v0 > 0.f) ? v0 : (LEAKY * v0);
  v1 = (v1 > 0.f) ? v1 : (LEAKY * v1);
  uint o = (uint)f2bf(v0) | ((uint)f2bf(v1) << 16);
  *reinterpret_cast<uint*>(&aggb[(long)node * F + f0]) = o;
  if constexpr (LAST) {
    float2 fo = make_float2(v0, v1);
    *reinterpret_cast<float2*>(&outh[(long)node * F + f0]) = fo;
  }
}

// ---------------- layer-1 GEMM fused with CSR fill ----------------
__global__ __launch_bounds__(256) void k_gemm1_csr(
    const ushort* __restrict__ Ab, const ushort* __restrict__ Bb,
    ushort* __restrict__ Cb, int M, int Nc, int K, int ldc, int gemmRows,
    const int* __restrict__ src, const int* __restrict__ dst,
    const float* __restrict__ dinv, int* __restrict__ cursor,
    unsigned long long* __restrict__ epack, int E) {
  constexpr int BM = 64;
  constexpr int MI = BM / 32;
  __shared__ __align__(16) ushort lds[(BM + 128) * 128];

  if (blockIdx.y >= gemmRows) {
    int i = ((blockIdx.y - gemmRows) * 2 + blockIdx.x) * 256 + threadIdx.x;
    if (i < E) {
      int d = dst[i];
      int s = src[i];
      int pos = atomicAdd(&cursor[d], 1);
      float nm = dinv[s] * dinv[d];
      unsigned long long pk = ((unsigned long long)__float_as_uint(nm) << 32) |
                              (unsigned long long)(unsigned)s;
      epack[pos] = pk;
    }
    return;
  }

  ushort* ldsA = lds;
  ushort* ldsB = lds + BM * 128;

  const int tid = threadIdx.x;
  const int lane = tid & 63;
  const int wv = tid >> 6;
  const int wr = wv >> 1, wc = wv & 1;
  const long bm = (long)blockIdx.y * BM;
  const long bn = (long)blockIdx.x * 128;

  f32x4 acc[MI][4];
#pragma unroll
  for (int i = 0; i < MI; i++)
#pragma unroll
    for (int j = 0; j < 4; j++) acc[i][j] = (f32x4){0.f, 0.f, 0.f, 0.f};

  const int kb = ((lane >> 4) << 4);

  for (int k0 = 0; k0 < K; k0 += 128) {
#pragma unroll
    for (int it = 0; it < BM / 16; it++) {
      int off = it * 4096 + tid * 16;
      int row = off >> 8;
      int cb = off & 255;
      long gr = bm + row;
      uint4 v = make_uint4(0u, 0u, 0u, 0u);
      if (gr < M) v = *reinterpret_cast<const uint4*>(&Ab[gr * K + k0 + (cb >> 1)]);
      int sb = (row << 8) | (cb ^ ((row & 7) << 4));
      *reinterpret_cast<uint4*>((char*)ldsA + sb) = v;
    }
#pragma unroll
    for (int it = 0; it < 8; it++) {
      int off = it * 4096 + tid * 16;
      int row = off >> 8;
      int cb = off & 255;
      long gn = bn + row;
      uint4 v = make_uint4(0u, 0u, 0u, 0u);
      if (gn < Nc) v = *reinterpret_cast<const uint4*>(&Bb[gn * K + k0 + (cb >> 1)]);
      int sb = (row << 8) | (cb ^ ((row & 7) << 4));
      *reinterpret_cast<uint4*>((char*)ldsB + sb) = v;
    }
    __syncthreads();

#pragma unroll
    for (int ks = 0; ks < 4; ks++) {
      short8 af[MI], bfr[4];
#pragma unroll
      for (int mi = 0; mi < MI; mi++) {
        int row = wr * (BM / 2) + mi * 16 + (lane & 15);
        int b = ks * 64 + kb;
        int addr = (row << 8) | (b ^ ((row & 7) << 4));
        af[mi] = *reinterpret_cast<const short8*>((const char*)ldsA + addr);
      }
#pragma unroll
      for (int ni = 0; ni < 4; ni++) {
        int row = wc * 64 + ni * 16 + (lane & 15);
        int b = ks * 64 + kb;
        int addr = (row << 8) | (b ^ ((row & 7) << 4));
        bfr[ni] = *reinterpret_cast<const short8*>((const char*)ldsB + addr);
      }
#pragma unroll
      for (int mi = 0; mi < MI; mi++)
#pragma unroll
        for (int ni = 0; ni < 4; ni++)
          acc[mi][ni] = __builtin_amdgcn_mfma_f32_16x16x32_bf16(af[mi], bfr[ni], acc[mi][ni], 0, 0, 0);
    }
    __syncthreads();
  }

#pragma unroll
  for (int ni = 0; ni < 4; ni++) {
    long col = bn + wc * 64 + ni * 16 + (lane & 15);
    if (col >= Nc) continue;
#pragma unroll
    for (int mi = 0; mi < MI; mi++) {
      long rbase2 = bm + wr * (BM / 2) + mi * 16 + ((lane >> 4) << 2);
#pragma unroll
      for (int j = 0; j < 4; j++) {
        long row = rbase2 + j;
        if (row >= M) continue;
        Cb[row * ldc + col] = f2bf(acc[mi][ni][j]);
      }
    }
  }
}

// ---------------- bf16 MFMA GEMM-BT (layer 2), BM=64, bf16 out ----------------
template <int BM>
__global__ __launch_bounds__(256) void k_gemm_bt(const ushort* __restrict__ Ab,
                                                 const ushort* __restrict__ Bb,
                                                 ushort* __restrict__ Cb,
                                                 int M, int N, int K, int ldc) {
  constexpr int MI = BM / 32;
  __shared__ __align__(16) ushort lds[(BM + 128) * 128];
  ushort* ldsA = lds;
  ushort* ldsB = lds + BM * 128;

  const int tid = threadIdx.x;
  const int lane = tid & 63;
  const int wv = tid >> 6;
  const int wr = wv >> 1, wc = wv & 1;
  const long bm = (long)blockIdx.y * BM;
  const long bn = (long)blockIdx.x * 128;

  f32x4 acc[MI][4];
#pragma unroll
  for (int i = 0; i < MI; i++)
#pragma unroll
    for (int j = 0; j < 4; j++) acc[i][j] = (f32x4){0.f, 0.f, 0.f, 0.f};

  const int kb = ((lane >> 4) << 4);

  for (int k0 = 0; k0 < K; k0 += 128) {
#pragma unroll
    for (int it = 0; it < BM / 16; it++) {
      int off = it * 4096 + tid * 16;
      int row = off >> 8;
      int cb = off & 255;
      long gr = bm + row;
      uint4 v = make_uint4(0u, 0u, 0u, 0u);
      if (gr < M) v = *reinterpret_cast<const uint4*>(&Ab[gr * K + k0 + (cb >> 1)]);
      int sb = (row << 8) | (cb ^ ((row & 7) << 4));
      *reinterpret_cast<uint4*>((char*)ldsA + sb) = v;
    }
#pragma unroll
    for (int it = 0; it < 8; it++) {
      int off = it * 4096 + tid * 16;
      int row = off >> 8;
      int cb = off & 255;
      long gn = bn + row;
      uint4 v = make_uint4(0u, 0u, 0u, 0u);
      if (gn < N) v = *reinterpret_cast<const uint4*>(&Bb[gn * K + k0 + (cb >> 1)]);
      int sb = (row << 8) | (cb ^ ((row & 7) << 4));
      *reinterpret_cast<uint4*>((char*)ldsB + sb) = v;
    }
    __syncthreads();

#pragma unroll
    for (int ks = 0; ks < 4; ks++) {
      short8 af[MI], bfr[4];
#pragma unroll
      for (int mi = 0; mi < MI; mi++) {
        int row = wr * (BM / 2) + mi * 16 + (lane & 15);
        int b = ks * 64 + kb;
        int addr = (row << 8) | (b ^ ((row & 7) << 4));
        af[mi] = *reinterpret_cast<const short8*>((const char*)ldsA + addr);
      }
#pragma unroll
      for (int ni = 0; ni < 4; ni++) {
        int row = wc * 64 + ni * 16 + (lane & 15);
        int b = ks * 64 + kb;
        int addr = (row << 8) | (b ^ ((row & 7) << 4));
        bfr[ni] = *reinterpret_cast<const short8*>((const char*)ldsB + addr);
      }
#pragma unroll
      for (int mi = 0; mi < MI; mi++)
#pragma unroll
        for (int ni = 0; ni < 4; ni++)
          acc[mi][ni] = __builtin_amdgcn_mfma_f32_16x16x32_bf16(af[mi], bfr[ni], acc[mi][ni], 0, 0, 0);
    }
    __syncthreads();
  }

#pragma unroll
  for (int ni = 0; ni < 4; ni++) {
    long col = bn + wc * 64 + ni * 16 + (lane & 15);
    if (col >= N) continue;
#pragma unroll
    for (int mi = 0; mi < MI; mi++) {
      long rbase2 = bm + wr * (BM / 2) + mi * 16 + ((lane >> 4) << 2);
#pragma unroll
      for (int j = 0; j < 4; j++) {
        long row = rbase2 + j;
        if (row >= M) continue;
        Cb[row * ldc + col] = f2bf(acc[mi][ni][j]);
      }
    }
  }
}

// ---------------- symmetric decode (R11 form): x1 = sigmoid(H H^T) ----------------
__global__ __launch_bounds__(256) void k_decode_sym(const ushort* __restrict__ Hb,
                                                    float* __restrict__ C, int N) {
  __shared__ __align__(16) ushort lds[2 * 128 * 128];
  ushort* ldsA = lds;
  ushort* ldsB = lds + 128 * 128;

  const int tid = threadIdx.x;
  const int lane = tid & 63;
  const int wv = tid >> 6;
  const int wr = wv >> 1, wc = wv & 1;

  int t = blockIdx.x;
  int bi = (int)((sqrtf(8.f * (float)t + 1.f) - 1.f) * 0.5f);
  while ((bi + 1) * (bi + 2) / 2 <= t) bi++;
  while (bi * (bi + 1) / 2 > t) bi--;
  int bj = t - bi * (bi + 1) / 2;
  const long bm = (long)bi * 128;
  const long bn = (long)bj * 128;

#pragma unroll
  for (int s = 0; s < 2; s++) {
    long rbase = s ? bn : bm;
    ushort* L = s ? ldsB : ldsA;
#pragma unroll
    for (int it = 0; it < 8; it++) {
      int off = it * 4096 + tid * 16;
      int row = off >> 8;
      int cb = off & 255;
      long grow = rbase + row;
      uint4 v = make_uint4(0u, 0u, 0u, 0u);
      if (grow < N)
        v = *reinterpret_cast<const uint4*>(&Hb[grow * 128 + (cb >> 1)]);
      int sb = (row << 8) | (cb ^ ((row & 7) << 4));
      *reinterpret_cast<uint4*>((char*)L + sb) = v;
    }
  }
  __syncthreads();

  f32x4 acc[4][4];
#pragma unroll
  for (int i = 0; i < 4; i++)
#pragma unroll
    for (int j = 0; j < 4; j++) acc[i][j] = (f32x4){0.f, 0.f, 0.f, 0.f};

  const int kb = ((lane >> 4) << 4);
#pragma unroll
  for (int ks = 0; ks < 4; ks++) {
    short8 af[4], bfr[4];
#pragma unroll
    for (int mi = 0; mi < 4; mi++) {
      int row = wr * 64 + mi * 16 + (lane & 15);
      int b = ks * 64 + kb;
      int addr = (row << 8) | (b ^ ((row & 7) << 4));
      af[mi] = *reinterpret_cast<const short8*>((const char*)ldsA + addr);
    }
#pragma unroll
    for (int ni = 0; ni < 4; ni++) {
      int row = wc * 64 + ni * 16 + (lane & 15);
      int b = ks * 64 + kb;
      int addr = (row << 8) | (b ^ ((row & 7) << 4));
      bfr[ni] = *reinterpret_cast<const short8*>((const char*)ldsB + addr);
    }
#pragma unroll
    for (int mi = 0; mi < 4; mi++)
#pragma unroll
      for (int ni = 0; ni < 4; ni++)
        acc[mi][ni] = __builtin_amdgcn_mfma_f32_16x16x32_bf16(af[mi], bfr[ni], acc[mi][ni], 0, 0, 0);
  }

#pragma unroll
  for (int mi = 0; mi < 4; mi++)
#pragma unroll
    for (int ni = 0; ni < 4; ni++)
#pragma unroll
      for (int j = 0; j < 4; j++)
        acc[mi][ni][j] = __builtin_amdgcn_rcpf(1.f + __expf(-acc[mi][ni][j]));

  if (bi != bj) {
#pragma unroll
    for (int ni = 0; ni < 4; ni++) {
      long gr = bn + wc * 64 + ni * 16 + (lane & 15);
#pragma unroll
      for (int mi = 0; mi < 4; mi++) {
        long gc = bm + wr * 64 + mi * 16 + ((lane >> 4) << 2);
        if (gr < N && gc < N)
          __builtin_nontemporal_store(acc[mi][ni],
                                      reinterpret_cast<f32x4*>(&C[gr * N + gc]));
      }
    }
  }

  __syncthreads();

  float* ft = (float*)lds;
#pragma unroll
  for (int ni = 0; ni < 4; ni++) {
    int col = wc * 64 + ni * 16 + (lane & 15);
#pragma unroll
    for (int mi = 0; mi < 4; mi++) {
      int rb = wr * 64 + mi * 16 + ((lane >> 4) << 2);
#pragma unroll
      for (int j = 0; j < 4; j++) {
        int row = rb + j;
        int byte = (row << 9) + (col << 2);
        byte ^= ((row & 7) << 4);
        *reinterpret_cast<float*>((char*)ft + byte) = acc[mi][ni][j];
      }
    }
  }
  __syncthreads();

#pragma unroll
  for (int it = 0; it < 16; it++) {
    int r = (tid >> 5) + it * 8;
    int ch = tid & 31;
    int byte = (r << 9) + (ch << 4);
    byte ^= ((r & 7) << 4);
    f32x4 v = *reinterpret_cast<const f32x4*>((const char*)ft + byte);
    long gr = bm + r;
    long gc = bn + ch * 4;
    if (gr < N && gc < N)
      __builtin_nontemporal_store(v, reinterpret_cast<f32x4*>(&C[gr * N + gc]));
  }
}

// ---------------- launch ----------------

extern "C" void kernel_launch(void* const* d_in, const int* in_sizes, int n_in,
                              void* d_out, int out_size, void* d_ws, size_t ws_size,
                              hipStream_t stream) {
  const float* x  = (const float*)d_in[0];
  const int*   ei = (const int*)d_in[1];
  const float* W1 = (const float*)d_in[3];
  const float* b1 = (const float*)d_in[4];
  const float* W2 = (const float*)d_in[5];
  const float* b2 = (const float*)d_in[6];

  const int N   = in_sizes[2];          // 10000
  const int E   = in_sizes[1] / 2;      // 320000
  const int Fin = in_sizes[0] / N;      // 512
  const int F1  = in_sizes[4];          // 256
  const int F2  = in_sizes[6];          // 128

  const int* src = ei;
  const int* dst = ei + E;

  float* ws = (float*)d_ws;
  ushort* w1t      = (ushort*)ws;
  ushort* w2t      = (ushort*)(ws + 65536);
  ushort* xb       = (ushort*)(ws + 81920);
  ushort* h1b      = (ushort*)(ws + 2641920);
  ushort* agg1b    = (ushort*)(ws + 3921920);
  ushort* h2b      = (ushort*)(ws + 5201920);
  ushort* hb       = (ushort*)(ws + 5841920);
  float*  dinv     = ws + 6481920;
  int*    cnt      = (int*)(ws + 6492160);
  int*    cursor   = (int*)(ws + 6502400);
  int*    rowstart = (int*)(ws + 6512640);
  unsigned long long* epack = (unsigned long long*)(ws + 6523136);

  float* out_x1 = (float*)d_out;
  float* out_h  = out_x1 + (long)N * N;

  hipMemsetAsync(cnt, 0, (size_t)N * sizeof(int), stream);
  {
    long xq = (long)N * Fin / 4;
    long tot = xq + (long)Fin * F1 + (long)F1 * F2;
    long thr = (tot > (long)E) ? tot : (long)E;
    k_count_prep<<<(unsigned)((thr + 255) / 256), 256, 0, stream>>>(
        dst, cnt, E, x, xb, xq, W1, w1t, Fin, F1, W2, w2t, F1, F2);
  }
  k_scan<<<1, 1024, 0, stream>>>(cnt, rowstart, cursor, dinv, N, E);

  {
    int gemmRows = (N + 63) / 64;
    int csrRows  = (E + 511) / 512;
    dim3 grid(F1 / 128, gemmRows + csrRows);
    k_gemm1_csr<<<grid, 256, 0, stream>>>(xb, w1t, h1b, N, F1, Fin, F1, gemmRows,
                                          src, dst, dinv, cursor, epack, E);
  }
  k_agg<256, 2, false><<<N, 128, 0, stream>>>(h1b, dinv, rowstart, epack, b1,
                                              agg1b, nullptr, N);

  {
    dim3 grid(F2 / 128, (N + 63) / 64);
    k_gemm_bt<64><<<grid, 256, 0, stream>>>(agg1b, w2t, h2b, N, F2, F1, F2);
  }
  k_agg<128, 1, true><<<N, 64, 0, stream>>>(h2b, dinv, rowstart, epack, b2,
                                            hb, out_h, N);

  // decode: MEASUREMENT ROUND — launched 5x (4 extra, idempotent: identical
  // values to identical addresses). dur_us = T_rest + 5*T_decode; R15 gave
  // T_rest + T_decode = 233.5, so T_decode = (dur_us - 233.5) / 4.
  {
    int NB = (N + 127) / 128;
    int nblk = NB * (NB + 1) / 2;
    for (int rep = 0; rep < 5; rep++)
      k_decode_sym<<<nblk, 256, 0, stream>>>(hb, out_x1, N);
  }
}

// Round 17
// 517.549 us; speedup vs baseline: 1.2867x; 1.2867x over previous
//
#include <hip/hip_runtime.h>
#include <hip/hip_cooperative_groups.h>
#include <math.h>

namespace cg = cooperative_groups;

#define LEAKY 0.01f

using short8   = __attribute__((ext_vector_type(8))) short;
using f32x4    = __attribute__((ext_vector_type(4))) float;
using ushort4e = __attribute__((ext_vector_type(4))) unsigned short;

__device__ __forceinline__ ushort f2bf(float f) {
  uint u = __float_as_uint(f);
  uint r = (u + 0x7FFFu + ((u >> 16) & 1u)) >> 16;
  return (ushort)r;
}
__device__ __forceinline__ float bf2f(ushort h) {
  uint u = ((uint)h) << 16;
  return __uint_as_float(u);
}

struct ChainArgs {
  const int* src; const int* dst; int E;
  const float* X; ushort* Xb; long xq;
  const float* W1; ushort* W1t; int K1; int N1;   // 512, 256
  const float* W2; ushort* W2t; int K2; int N2;   // 256, 128
  int* cnt; int* rowstart; int* cursor; float* dinv;
  unsigned long long* epack;
  ushort* h1b; ushort* agg1b; const float* b1;
  ushort* h2b; ushort* hb; float* outh; const float* b2;
  int N;
};

// ---- shared gemm tile body (BM=64, BN=128), smem = 49152B ----
__device__ void gemm_tile(char* smem, const ushort* __restrict__ Ab,
                          const ushort* __restrict__ Bb, ushort* __restrict__ Cb,
                          int M, int Nc, int K, int ldc, long bm, long bn) {
  constexpr int BM = 64, MI = 2;
  ushort* ldsA = (ushort*)smem;
  ushort* ldsB = (ushort*)smem + BM * 128;

  const int tid = threadIdx.x;
  const int lane = tid & 63;
  const int wv = tid >> 6;
  const int wr = wv >> 1, wc = wv & 1;

  f32x4 acc[MI][4];
#pragma unroll
  for (int i = 0; i < MI; i++)
#pragma unroll
    for (int j = 0; j < 4; j++) acc[i][j] = (f32x4){0.f, 0.f, 0.f, 0.f};

  const int kb = ((lane >> 4) << 4);

  for (int k0 = 0; k0 < K; k0 += 128) {
#pragma unroll
    for (int it = 0; it < BM / 16; it++) {
      int off = it * 4096 + tid * 16;
      int row = off >> 8;
      int cb = off & 255;
      long gr = bm + row;
      uint4 v = make_uint4(0u, 0u, 0u, 0u);
      if (gr < M) v = *reinterpret_cast<const uint4*>(&Ab[gr * K + k0 + (cb >> 1)]);
      int sb = (row << 8) | (cb ^ ((row & 7) << 4));
      *reinterpret_cast<uint4*>((char*)ldsA + sb) = v;
    }
#pragma unroll
    for (int it = 0; it < 8; it++) {
      int off = it * 4096 + tid * 16;
      int row = off >> 8;
      int cb = off & 255;
      long gn = bn + row;
      uint4 v = make_uint4(0u, 0u, 0u, 0u);
      if (gn < Nc) v = *reinterpret_cast<const uint4*>(&Bb[gn * K + k0 + (cb >> 1)]);
      int sb = (row << 8) | (cb ^ ((row & 7) << 4));
      *reinterpret_cast<uint4*>((char*)ldsB + sb) = v;
    }
    __syncthreads();

#pragma unroll
    for (int ks = 0; ks < 4; ks++) {
      short8 af[MI], bfr[4];
#pragma unroll
      for (int mi = 0; mi < MI; mi++) {
        int row = wr * (BM / 2) + mi * 16 + (lane & 15);
        int b = ks * 64 + kb;
        int addr = (row << 8) | (b ^ ((row & 7) << 4));
        af[mi] = *reinterpret_cast<const short8*>((const char*)ldsA + addr);
      }
#pragma unroll
      for (int ni = 0; ni < 4; ni++) {
        int row = wc * 64 + ni * 16 + (lane & 15);
        int b = ks * 64 + kb;
        int addr = (row << 8) | (b ^ ((row & 7) << 4));
        bfr[ni] = *reinterpret_cast<const short8*>((const char*)ldsB + addr);
      }
#pragma unroll
      for (int mi = 0; mi < MI; mi++)
#pragma unroll
        for (int ni = 0; ni < 4; ni++)
          acc[mi][ni] = __builtin_amdgcn_mfma_f32_16x16x32_bf16(af[mi], bfr[ni], acc[mi][ni], 0, 0, 0);
    }
    __syncthreads();
  }

#pragma unroll
  for (int ni = 0; ni < 4; ni++) {
    long col = bn + wc * 64 + ni * 16 + (lane & 15);
    if (col >= Nc) continue;
#pragma unroll
    for (int mi = 0; mi < MI; mi++) {
      long rbase2 = bm + wr * (BM / 2) + mi * 16 + ((lane >> 4) << 2);
#pragma unroll
      for (int j = 0; j < 4; j++) {
        long row = rbase2 + j;
        if (row >= M) continue;
        Cb[row * ldc + col] = f2bf(acc[mi][ni][j]);
      }
    }
  }
}

// ---- per-node gather aggregation body; t in [0, F/2) ----
template <int F, bool LAST>
__device__ void agg_node(const ChainArgs& a, const ushort* __restrict__ hlin,
                         const float* __restrict__ bias, ushort* __restrict__ aggb,
                         float* __restrict__ outh, int node, int t) {
  const int f0 = ((t >> 6) << 7) + ((t & 63) << 1);
  const float di = a.dinv[node];
  float acc0, acc1;
  {
    uint v = *reinterpret_cast<const uint*>(&hlin[(long)node * F + f0]);
    float dd = di * di;
    acc0 = bf2f((ushort)(v & 0xffff)) * dd;
    acc1 = bf2f((ushort)(v >> 16)) * dd;
  }
  const int e0 = a.rowstart[node], e1 = a.rowstart[node + 1];
  int e = e0;
  for (; e + 7 < e1; e += 8) {
#pragma unroll
    for (int u = 0; u < 8; u++) {
      unsigned long long pk = a.epack[e + u];
      int s = (int)(unsigned)(pk & 0xffffffffull);
      float nm = __uint_as_float((uint)(pk >> 32));
      uint v = *reinterpret_cast<const uint*>(&hlin[(long)s * F + f0]);
      acc0 += bf2f((ushort)(v & 0xffff)) * nm;
      acc1 += bf2f((ushort)(v >> 16)) * nm;
    }
  }
  for (; e < e1; e++) {
    unsigned long long pk = a.epack[e];
    int s = (int)(unsigned)(pk & 0xffffffffull);
    float nm = __uint_as_float((uint)(pk >> 32));
    uint v = *reinterpret_cast<const uint*>(&hlin[(long)s * F + f0]);
    acc0 += bf2f((ushort)(v & 0xffff)) * nm;
    acc1 += bf2f((ushort)(v >> 16)) * nm;
  }
  float v0 = acc0 + bias[f0];
  float v1 = acc1 + bias[f0 + 1];
  v0 = (v0 > 0.f) ? v0 : (LEAKY * v0);
  v1 = (v1 > 0.f) ? v1 : (LEAKY * v1);
  uint o = (uint)f2bf(v0) | ((uint)f2bf(v1) << 16);
  *reinterpret_cast<uint*>(&aggb[(long)node * F + f0]) = o;
  if constexpr (LAST) {
    float2 fo = make_float2(v0, v1);
    *reinterpret_cast<float2*>(&outh[(long)node * F + f0]) = fo;
  }
}

// ---- the fused chain: count+prep -> scan -> gemm1+csr -> agg1 -> gemm2 -> agg2 ----
__global__ __launch_bounds__(256, 2) void k_chain(ChainArgs a) {
  cg::grid_group grid = cg::this_grid();
  __shared__ __align__(16) char smem[49152];
  const int nb = (int)gridDim.x;
  const int bid = (int)blockIdx.x;
  const int tid = (int)threadIdx.x;

  // P0: zero cnt
  for (int i = bid * 256 + tid; i < a.N; i += nb * 256) a.cnt[i] = 0;
  grid.sync();

  // P1: degree count + bf16 prep
  {
    long tot = a.xq + (long)a.K1 * a.N1 + (long)a.K2 * a.N2;
    long lim = (tot > (long)a.E) ? tot : (long)a.E;
    for (long i = (long)bid * 256 + tid; i < lim; i += (long)nb * 256) {
      if (i < a.E) atomicAdd(&a.cnt[a.dst[i]], 1);
      if (i < a.xq) {
        long b = i * 4;
        float4 v = *reinterpret_cast<const float4*>(&a.X[b]);
        ushort4e u = {f2bf(v.x), f2bf(v.y), f2bf(v.z), f2bf(v.w)};
        *reinterpret_cast<ushort4e*>(&a.Xb[b]) = u;
      } else {
        long j = i - a.xq;
        long t1 = (long)a.K1 * a.N1;
        if (j < t1) {
          int k = (int)(j / a.N1), n = (int)(j % a.N1);
          a.W1t[(long)n * a.K1 + k] = f2bf(a.W1[j]);
        } else if (j < t1 + (long)a.K2 * a.N2) {
          long jj = j - t1;
          int k = (int)(jj / a.N2), n = (int)(jj % a.N2);
          a.W2t[(long)n * a.K2 + k] = f2bf(a.W2[jj]);
        }
      }
    }
  }
  grid.sync();

  // P2: scan + dinv + cursors (block 0, 256 threads, 40 nodes/thread)
  if (bid == 0) {
    int* part = (int*)smem;
    const int CH = 40;
    int base = tid * CH;
    int s = 0;
    for (int i = 0; i < CH; i++) {
      int nd = base + i;
      if (nd < a.N) s += a.cnt[nd];
    }
    part[tid] = s;
    __syncthreads();
    for (int off = 1; off < 256; off <<= 1) {
      int add = (tid >= off) ? part[tid - off] : 0;
      __syncthreads();
      part[tid] += add;
      __syncthreads();
    }
    int run = (tid == 0) ? 0 : part[tid - 1];
    for (int i = 0; i < CH; i++) {
      int nd = base + i;
      if (nd < a.N) {
        int v = a.cnt[nd];
        a.dinv[nd] = rsqrtf((float)v + 1.0f);
        a.rowstart[nd] = run;
        a.cursor[nd] = run;
        run += v;
      }
    }
    if (tid == 255) a.rowstart[a.N] = a.E;
  }
  grid.sync();

  // P3: layer-1 GEMM tiles (grid-stride) + CSR fill (grid-stride)
  {
    int tiles = ((a.N + 63) / 64) * 2;   // col-tiles x row-tiles
    for (int t = bid; t < tiles; t += nb) {
      long bm = (long)(t >> 1) * 64;
      long bn = (long)(t & 1) * 128;
      gemm_tile(smem, a.Xb, a.W1t, a.h1b, a.N, a.N1, a.K1, a.N1, bm, bn);
    }
    for (long i = (long)bid * 256 + tid; i < a.E; i += (long)nb * 256) {
      int d = a.dst[i];
      int s = a.src[i];
      int pos = atomicAdd(&a.cursor[d], 1);
      float nm = a.dinv[s] * a.dinv[d];
      unsigned long long pk = ((unsigned long long)__float_as_uint(nm) << 32) |
                              (unsigned long long)(unsigned)s;
      a.epack[pos] = pk;
    }
  }
  grid.sync();

  // P4: agg1 (2 nodes per block pass; threads 0-127 node a, 128-255 node b)
  for (int base = bid * 2; base < a.N; base += nb * 2) {
    int node = base + (tid >> 7);
    if (node < a.N)
      agg_node<256, false>(a, a.h1b, a.b1, a.agg1b, nullptr, node, tid & 127);
  }
  grid.sync();

  // P5: layer-2 GEMM tiles
  {
    int tiles = (a.N + 63) / 64;
    for (int t = bid; t < tiles; t += nb) {
      long bm = (long)t * 64;
      gemm_tile(smem, a.agg1b, a.W2t, a.h2b, a.N, a.N2, a.K2, a.N2, bm, 0);
    }
  }
  grid.sync();

  // P6: agg2 (4 nodes per block pass; one wave per node) -> hb + out_h
  for (int base = bid * 4; base < a.N; base += nb * 4) {
    int node = base + (tid >> 6);
    if (node < a.N)
      agg_node<128, true>(a, a.h2b, a.b2, a.hb, a.outh, node, tid & 63);
  }
}

// ---------------- symmetric decode (R11 form): x1 = sigmoid(H H^T) ----------------
__global__ __launch_bounds__(256) void k_decode_sym(const ushort* __restrict__ Hb,
                                                    float* __restrict__ C, int N) {
  __shared__ __align__(16) ushort lds[2 * 128 * 128];
  ushort* ldsA = lds;
  ushort* ldsB = lds + 128 * 128;

  const int tid = threadIdx.x;
  const int lane = tid & 63;
  const int wv = tid >> 6;
  const int wr = wv >> 1, wc = wv & 1;

  int t = blockIdx.x;
  int bi = (int)((sqrtf(8.f * (float)t + 1.f) - 1.f) * 0.5f);
  while ((bi + 1) * (bi + 2) / 2 <= t) bi++;
  while (bi * (bi + 1) / 2 > t) bi--;
  int bj = t - bi * (bi + 1) / 2;
  const long bm = (long)bi * 128;
  const long bn = (long)bj * 128;

#pragma unroll
  for (int s = 0; s < 2; s++) {
    long rbase = s ? bn : bm;
    ushort* L = s ? ldsB : ldsA;
#pragma unroll
    for (int it = 0; it < 8; it++) {
      int off = it * 4096 + tid * 16;
      int row = off >> 8;
      int cb = off & 255;
      long grow = rbase + row;
      uint4 v = make_uint4(0u, 0u, 0u, 0u);
      if (grow < N)
        v = *reinterpret_cast<const uint4*>(&Hb[grow * 128 + (cb >> 1)]);
      int sb = (row << 8) | (cb ^ ((row & 7) << 4));
      *reinterpret_cast<uint4*>((char*)L + sb) = v;
    }
  }
  __syncthreads();

  f32x4 acc[4][4];
#pragma unroll
  for (int i = 0; i < 4; i++)
#pragma unroll
    for (int j = 0; j < 4; j++) acc[i][j] = (f32x4){0.f, 0.f, 0.f, 0.f};

  const int kb = ((lane >> 4) << 4);
#pragma unroll
  for (int ks = 0; ks < 4; ks++) {
    short8 af[4], bfr[4];
#pragma unroll
    for (int mi = 0; mi < 4; mi++) {
      int row = wr * 64 + mi * 16 + (lane & 15);
      int b = ks * 64 + kb;
      int addr = (row << 8) | (b ^ ((row & 7) << 4));
      af[mi] = *reinterpret_cast<const short8*>((const char*)ldsA + addr);
    }
#pragma unroll
    for (int ni = 0; ni < 4; ni++) {
      int row = wc * 64 + ni * 16 + (lane & 15);
      int b = ks * 64 + kb;
      int addr = (row << 8) | (b ^ ((row & 7) << 4));
      bfr[ni] = *reinterpret_cast<const short8*>((const char*)ldsB + addr);
    }
#pragma unroll
    for (int mi = 0; mi < 4; mi++)
#pragma unroll
      for (int ni = 0; ni < 4; ni++)
        acc[mi][ni] = __builtin_amdgcn_mfma_f32_16x16x32_bf16(af[mi], bfr[ni], acc[mi][ni], 0, 0, 0);
  }

#pragma unroll
  for (int mi = 0; mi < 4; mi++)
#pragma unroll
    for (int ni = 0; ni < 4; ni++)
#pragma unroll
      for (int j = 0; j < 4; j++)
        acc[mi][ni][j] = __builtin_amdgcn_rcpf(1.f + __expf(-acc[mi][ni][j]));

  if (bi != bj) {
#pragma unroll
    for (int ni = 0; ni < 4; ni++) {
      long gr = bn + wc * 64 + ni * 16 + (lane & 15);
#pragma unroll
      for (int mi = 0; mi < 4; mi++) {
        long gc = bm + wr * 64 + mi * 16 + ((lane >> 4) << 2);
        if (gr < N && gc < N)
          __builtin_nontemporal_store(acc[mi][ni],
                                      reinterpret_cast<f32x4*>(&C[gr * N + gc]));
      }
    }
  }

  __syncthreads();

  float* ft = (float*)lds;
#pragma unroll
  for (int ni = 0; ni < 4; ni++) {
    int col = wc * 64 + ni * 16 + (lane & 15);
#pragma unroll
    for (int mi = 0; mi < 4; mi++) {
      int rb = wr * 64 + mi * 16 + ((lane >> 4) << 2);
#pragma unroll
      for (int j = 0; j < 4; j++) {
        int row = rb + j;
        int byte = (row << 9) + (col << 2);
        byte ^= ((row & 7) << 4);
        *reinterpret_cast<float*>((char*)ft + byte) = acc[mi][ni][j];
      }
    }
  }
  __syncthreads();

#pragma unroll
  for (int it = 0; it < 16; it++) {
    int r = (tid >> 5) + it * 8;
    int ch = tid & 31;
    int byte = (r << 9) + (ch << 4);
    byte ^= ((r & 7) << 4);
    f32x4 v = *reinterpret_cast<const f32x4*>((const char*)ft + byte);
    long gr = bm + r;
    long gc = bn + ch * 4;
    if (gr < N && gc < N)
      __builtin_nontemporal_store(v, reinterpret_cast<f32x4*>(&C[gr * N + gc]));
  }
}

// ---------------- launch ----------------

extern "C" void kernel_launch(void* const* d_in, const int* in_sizes, int n_in,
                              void* d_out, int out_size, void* d_ws, size_t ws_size,
                              hipStream_t stream) {
  const float* x  = (const float*)d_in[0];
  const int*   ei = (const int*)d_in[1];
  const float* W1 = (const float*)d_in[3];
  const float* b1 = (const float*)d_in[4];
  const float* W2 = (const float*)d_in[5];
  const float* b2 = (const float*)d_in[6];

  const int N   = in_sizes[2];          // 10000
  const int E   = in_sizes[1] / 2;      // 320000
  const int Fin = in_sizes[0] / N;      // 512
  const int F1  = in_sizes[4];          // 256
  const int F2  = in_sizes[6];          // 128

  const int* src = ei;
  const int* dst = ei + E;

  float* ws = (float*)d_ws;
  ushort* w1t      = (ushort*)ws;
  ushort* w2t      = (ushort*)(ws + 65536);
  ushort* xb       = (ushort*)(ws + 81920);
  ushort* h1b      = (ushort*)(ws + 2641920);
  ushort* agg1b    = (ushort*)(ws + 3921920);
  ushort* h2b      = (ushort*)(ws + 5201920);
  ushort* hb       = (ushort*)(ws + 5841920);
  float*  dinv     = ws + 6481920;
  int*    cnt      = (int*)(ws + 6492160);
  int*    cursor   = (int*)(ws + 6502400);
  int*    rowstart = (int*)(ws + 6512640);
  unsigned long long* epack = (unsigned long long*)(ws + 6523136);

  float* out_x1 = (float*)d_out;
  float* out_h  = out_x1 + (long)N * N;

  ChainArgs ca;
  ca.src = src; ca.dst = dst; ca.E = E;
  ca.X = x; ca.Xb = xb; ca.xq = (long)N * Fin / 4;
  ca.W1 = W1; ca.W1t = w1t; ca.K1 = Fin; ca.N1 = F1;
  ca.W2 = W2; ca.W2t = w2t; ca.K2 = F1; ca.N2 = F2;
  ca.cnt = cnt; ca.rowstart = rowstart; ca.cursor = cursor; ca.dinv = dinv;
  ca.epack = epack;
  ca.h1b = h1b; ca.agg1b = agg1b; ca.b1 = b1;
  ca.h2b = h2b; ca.hb = hb; ca.outh = out_h; ca.b2 = b2;
  ca.N = N;

  // cooperative chain: grid clamped to guaranteed co-residency
  {
    int maxPerCU = 0;
    int nb = 512;
    if (hipOccupancyMaxActiveBlocksPerMultiprocessor(&maxPerCU, k_chain, 256, 0) ==
            hipSuccess && maxPerCU >= 1) {
      long cap = (long)maxPerCU * 256;   // 256 CUs
      if (cap < nb) nb = (int)cap;
    }
    void* args[] = {(void*)&ca};
    hipLaunchCooperativeKernel((const void*)k_chain, dim3(nb), dim3(256), args, 0,
                               stream);
  }

  // decode: x1 = sigmoid(h @ h^T), symmetric triangular grid
  {
    int NB = (N + 127) / 128;
    int nblk = NB * (NB + 1) / 2;
    k_decode_sym<<<nblk, 256, 0, stream>>>(hb, out_x1, N);
  }
}

// Round 18
// 241.608 us; speedup vs baseline: 2.7562x; 2.1421x over previous
//
#include <hip/hip_runtime.h>
#include <math.h>

#define LEAKY 0.01f

using short8   = __attribute__((ext_vector_type(8))) short;
using f32x4    = __attribute__((ext_vector_type(4))) float;
using ushort4e = __attribute__((ext_vector_type(4))) unsigned short;

__device__ __forceinline__ ushort f2bf(float f) {
  uint u = __float_as_uint(f);
  uint r = (u + 0x7FFFu + ((u >> 16) & 1u)) >> 16;
  return (ushort)r;
}
__device__ __forceinline__ float bf2f(ushort h) {
  uint u = ((uint)h) << 16;
  return __uint_as_float(u);
}

// ---------------- fused: degree count + x/W -> bf16 prep ----------------

__global__ void k_count_prep(const int* __restrict__ dst, int* __restrict__ cnt, int E,
                             const float* __restrict__ X, ushort* __restrict__ Xb, long xq,
                             const float* __restrict__ W1, ushort* __restrict__ Wt1,
                             int K1, int N1,
                             const float* __restrict__ W2, ushort* __restrict__ Wt2,
                             int K2, int N2) {
  long i = (long)blockIdx.x * blockDim.x + threadIdx.x;
  if (i < E) atomicAdd(&cnt[dst[i]], 1);
  if (i < xq) {
    long b = i * 4;
    float4 v = *reinterpret_cast<const float4*>(&X[b]);
    ushort4e u = {f2bf(v.x), f2bf(v.y), f2bf(v.z), f2bf(v.w)};
    *reinterpret_cast<ushort4e*>(&Xb[b]) = u;
  } else {
    long j = i - xq;
    long t1 = (long)K1 * N1;
    if (j < t1) {
      int k = (int)(j / N1), n = (int)(j % N1);
      Wt1[(long)n * K1 + k] = f2bf(W1[j]);
    } else if (j < t1 + (long)K2 * N2) {
      long jj = j - t1;
      int k = (int)(jj / N2), n = (int)(jj % N2);
      Wt2[(long)n * K2 + k] = f2bf(W2[jj]);
    }
  }
}

// single block, 1024 threads; N <= 16384. Also emits dinv = rsqrt(cnt+1).
__global__ void k_scan(const int* __restrict__ cnt, int* __restrict__ rowstart,
                       int* __restrict__ cursor, float* __restrict__ dinv,
                       int N, int Etot) {
  __shared__ int part[1024];
  const int t = threadIdx.x;
  const int CH = 16;
  int base = t * CH;
  int local[CH];
  int s = 0;
#pragma unroll
  for (int i = 0; i < CH; i++) {
    int v = (base + i < N) ? cnt[base + i] : 0;
    if (base + i < N) dinv[base + i] = rsqrtf((float)v + 1.0f);
    local[i] = s;
    s += v;
  }
  part[t] = s;
  __syncthreads();
  for (int off = 1; off < 1024; off <<= 1) {
    int add = (t >= off) ? part[t - off] : 0;
    __syncthreads();
    part[t] += add;
    __syncthreads();
  }
  int excl = (t == 0) ? 0 : part[t - 1];
#pragma unroll
  for (int i = 0; i < CH; i++) {
    if (base + i < N) {
      int rs = excl + local[i];
      rowstart[base + i] = rs;
      cursor[base + i] = rs;
    }
  }
  if (t == 0) rowstart[N] = Etot;
}

// ---------------- gather aggregation: bf16 in/out, packed edge records ----------------
template <int F, int WAVES, bool LAST>
__global__ __launch_bounds__(64 * WAVES) void k_agg(const ushort* __restrict__ hlin,
                                                    const float* __restrict__ dinv,
                                                    const int* __restrict__ rowstart,
                                                    const unsigned long long* __restrict__ epack,
                                                    const float* __restrict__ bias,
                                                    ushort* __restrict__ aggb,
                                                    float* __restrict__ outh, int N) {
  constexpr int FS = F / WAVES;
  const int node = blockIdx.x;
  const int tid = threadIdx.x;
  const int w = tid >> 6;
  const int lane = tid & 63;
  const int f0 = w * FS + lane * 2;
  const float di = dinv[node];

  float acc0, acc1;
  {
    uint v = *reinterpret_cast<const uint*>(&hlin[(long)node * F + f0]);
    float dd = di * di;
    acc0 = bf2f((ushort)(v & 0xffff)) * dd;
    acc1 = bf2f((ushort)(v >> 16)) * dd;
  }
  const int e0 = rowstart[node], e1 = rowstart[node + 1];
  int e = e0;
  for (; e + 7 < e1; e += 8) {
#pragma unroll
    for (int u = 0; u < 8; u++) {
      unsigned long long pk = epack[e + u];
      int s = (int)(unsigned)(pk & 0xffffffffull);
      float nm = __uint_as_float((uint)(pk >> 32));
      uint v = *reinterpret_cast<const uint*>(&hlin[(long)s * F + f0]);
      acc0 += bf2f((ushort)(v & 0xffff)) * nm;
      acc1 += bf2f((ushort)(v >> 16)) * nm;
    }
  }
  for (; e < e1; e++) {
    unsigned long long pk = epack[e];
    int s = (int)(unsigned)(pk & 0xffffffffull);
    float nm = __uint_as_float((uint)(pk >> 32));
    uint v = *reinterpret_cast<const uint*>(&hlin[(long)s * F + f0]);
    acc0 += bf2f((ushort)(v & 0xffff)) * nm;
    acc1 += bf2f((ushort)(v >> 16)) * nm;
  }

  float v0 = acc0 + bias[f0];
  float v1 = acc1 + bias[f0 + 1];
  v0 = (v0 > 0.f) ? v0 : (LEAKY * v0);
  v1 = (v1 > 0.f) ? v1 : (LEAKY * v1);
  uint o = (uint)f2bf(v0) | ((uint)f2bf(v1) << 16);
  *reinterpret_cast<uint*>(&aggb[(long)node * F + f0]) = o;
  if constexpr (LAST) {
    float2 fo = make_float2(v0, v1);
    *reinterpret_cast<float2*>(&outh[(long)node * F + f0]) = fo;
  }
}

// ---------------- layer-1 GEMM fused with CSR fill ----------------
__global__ __launch_bounds__(256) void k_gemm1_csr(
    const ushort* __restrict__ Ab, const ushort* __restrict__ Bb,
    ushort* __restrict__ Cb, int M, int Nc, int K, int ldc, int gemmRows,
    const int* __restrict__ src, const int* __restrict__ dst,
    const float* __restrict__ dinv, int* __restrict__ cursor,
    unsigned long long* __restrict__ epack, int E) {
  constexpr int BM = 64;
  constexpr int MI = BM / 32;
  __shared__ __align__(16) ushort lds[(BM + 128) * 128];

  if (blockIdx.y >= gemmRows) {
    int i = ((blockIdx.y - gemmRows) * 2 + blockIdx.x) * 256 + threadIdx.x;
    if (i < E) {
      int d = dst[i];
      int s = src[i];
      int pos = atomicAdd(&cursor[d], 1);
      float nm = dinv[s] * dinv[d];
      unsigned long long pk = ((unsigned long long)__float_as_uint(nm) << 32) |
                              (unsigned long long)(unsigned)s;
      epack[pos] = pk;
    }
    return;
  }

  ushort* ldsA = lds;
  ushort* ldsB = lds + BM * 128;

  const int tid = threadIdx.x;
  const int lane = tid & 63;
  const int wv = tid >> 6;
  const int wr = wv >> 1, wc = wv & 1;
  const long bm = (long)blockIdx.y * BM;
  const long bn = (long)blockIdx.x * 128;

  f32x4 acc[MI][4];
#pragma unroll
  for (int i = 0; i < MI; i++)
#pragma unroll
    for (int j = 0; j < 4; j++) acc[i][j] = (f32x4){0.f, 0.f, 0.f, 0.f};

  const int kb = ((lane >> 4) << 4);

  for (int k0 = 0; k0 < K; k0 += 128) {
#pragma unroll
    for (int it = 0; it < BM / 16; it++) {
      int off = it * 4096 + tid * 16;
      int row = off >> 8;
      int cb = off & 255;
      long gr = bm + row;
      uint4 v = make_uint4(0u, 0u, 0u, 0u);
      if (gr < M) v = *reinterpret_cast<const uint4*>(&Ab[gr * K + k0 + (cb >> 1)]);
      int sb = (row << 8) | (cb ^ ((row & 7) << 4));
      *reinterpret_cast<uint4*>((char*)ldsA + sb) = v;
    }
#pragma unroll
    for (int it = 0; it < 8; it++) {
      int off = it * 4096 + tid * 16;
      int row = off >> 8;
      int cb = off & 255;
      long gn = bn + row;
      uint4 v = make_uint4(0u, 0u, 0u, 0u);
      if (gn < Nc) v = *reinterpret_cast<const uint4*>(&Bb[gn * K + k0 + (cb >> 1)]);
      int sb = (row << 8) | (cb ^ ((row & 7) << 4));
      *reinterpret_cast<uint4*>((char*)ldsB + sb) = v;
    }
    __syncthreads();

#pragma unroll
    for (int ks = 0; ks < 4; ks++) {
      short8 af[MI], bfr[4];
#pragma unroll
      for (int mi = 0; mi < MI; mi++) {
        int row = wr * (BM / 2) + mi * 16 + (lane & 15);
        int b = ks * 64 + kb;
        int addr = (row << 8) | (b ^ ((row & 7) << 4));
        af[mi] = *reinterpret_cast<const short8*>((const char*)ldsA + addr);
      }
#pragma unroll
      for (int ni = 0; ni < 4; ni++) {
        int row = wc * 64 + ni * 16 + (lane & 15);
        int b = ks * 64 + kb;
        int addr = (row << 8) | (b ^ ((row & 7) << 4));
        bfr[ni] = *reinterpret_cast<const short8*>((const char*)ldsB + addr);
      }
#pragma unroll
      for (int mi = 0; mi < MI; mi++)
#pragma unroll
        for (int ni = 0; ni < 4; ni++)
          acc[mi][ni] = __builtin_amdgcn_mfma_f32_16x16x32_bf16(af[mi], bfr[ni], acc[mi][ni], 0, 0, 0);
    }
    __syncthreads();
  }

#pragma unroll
  for (int ni = 0; ni < 4; ni++) {
    long col = bn + wc * 64 + ni * 16 + (lane & 15);
    if (col >= Nc) continue;
#pragma unroll
    for (int mi = 0; mi < MI; mi++) {
      long rbase2 = bm + wr * (BM / 2) + mi * 16 + ((lane >> 4) << 2);
#pragma unroll
      for (int j = 0; j < 4; j++) {
        long row = rbase2 + j;
        if (row >= M) continue;
        Cb[row * ldc + col] = f2bf(acc[mi][ni][j]);
      }
    }
  }
}

// ---------------- bf16 MFMA GEMM-BT (layer 2), BM=64, bf16 out ----------------
template <int BM>
__global__ __launch_bounds__(256) void k_gemm_bt(const ushort* __restrict__ Ab,
                                                 const ushort* __restrict__ Bb,
                                                 ushort* __restrict__ Cb,
                                                 int M, int N, int K, int ldc) {
  constexpr int MI = BM / 32;
  __shared__ __align__(16) ushort lds[(BM + 128) * 128];
  ushort* ldsA = lds;
  ushort* ldsB = lds + BM * 128;

  const int tid = threadIdx.x;
  const int lane = tid & 63;
  const int wv = tid >> 6;
  const int wr = wv >> 1, wc = wv & 1;
  const long bm = (long)blockIdx.y * BM;
  const long bn = (long)blockIdx.x * 128;

  f32x4 acc[MI][4];
#pragma unroll
  for (int i = 0; i < MI; i++)
#pragma unroll
    for (int j = 0; j < 4; j++) acc[i][j] = (f32x4){0.f, 0.f, 0.f, 0.f};

  const int kb = ((lane >> 4) << 4);

  for (int k0 = 0; k0 < K; k0 += 128) {
#pragma unroll
    for (int it = 0; it < BM / 16; it++) {
      int off = it * 4096 + tid * 16;
      int row = off >> 8;
      int cb = off & 255;
      long gr = bm + row;
      uint4 v = make_uint4(0u, 0u, 0u, 0u);
      if (gr < M) v = *reinterpret_cast<const uint4*>(&Ab[gr * K + k0 + (cb >> 1)]);
      int sb = (row << 8) | (cb ^ ((row & 7) << 4));
      *reinterpret_cast<uint4*>((char*)ldsA + sb) = v;
    }
#pragma unroll
    for (int it = 0; it < 8; it++) {
      int off = it * 4096 + tid * 16;
      int row = off >> 8;
      int cb = off & 255;
      long gn = bn + row;
      uint4 v = make_uint4(0u, 0u, 0u, 0u);
      if (gn < N) v = *reinterpret_cast<const uint4*>(&Bb[gn * K + k0 + (cb >> 1)]);
      int sb = (row << 8) | (cb ^ ((row & 7) << 4));
      *reinterpret_cast<uint4*>((char*)ldsB + sb) = v;
    }
    __syncthreads();

#pragma unroll
    for (int ks = 0; ks < 4; ks++) {
      short8 af[MI], bfr[4];
#pragma unroll
      for (int mi = 0; mi < MI; mi++) {
        int row = wr * (BM / 2) + mi * 16 + (lane & 15);
        int b = ks * 64 + kb;
        int addr = (row << 8) | (b ^ ((row & 7) << 4));
        af[mi] = *reinterpret_cast<const short8*>((const char*)ldsA + addr);
      }
#pragma unroll
      for (int ni = 0; ni < 4; ni++) {
        int row = wc * 64 + ni * 16 + (lane & 15);
        int b = ks * 64 + kb;
        int addr = (row << 8) | (b ^ ((row & 7) << 4));
        bfr[ni] = *reinterpret_cast<const short8*>((const char*)ldsB + addr);
      }
#pragma unroll
      for (int mi = 0; mi < MI; mi++)
#pragma unroll
        for (int ni = 0; ni < 4; ni++)
          acc[mi][ni] = __builtin_amdgcn_mfma_f32_16x16x32_bf16(af[mi], bfr[ni], acc[mi][ni], 0, 0, 0);
    }
    __syncthreads();
  }

#pragma unroll
  for (int ni = 0; ni < 4; ni++) {
    long col = bn + wc * 64 + ni * 16 + (lane & 15);
    if (col >= N) continue;
#pragma unroll
    for (int mi = 0; mi < MI; mi++) {
      long rbase2 = bm + wr * (BM / 2) + mi * 16 + ((lane >> 4) << 2);
#pragma unroll
      for (int j = 0; j < 4; j++) {
        long row = rbase2 + j;
        if (row >= M) continue;
        Cb[row * ldc + col] = f2bf(acc[mi][ni][j]);
      }
    }
  }
}

// ---------------- symmetric decode, LDS-light: x1 = sigmoid(H H^T) ----------------
// Triangular grid. NO LDS staging: MFMA fragments read DIRECTLY from global Hb
// (2.56MB, L2-resident; each fragment-load instr touches 16 full 64B lines).
// LDS = 32KB f32 bounce only -> ~4 blocks/CU (VGPR-bound) vs 2 before: 2x the
// store-drain parallelism. Transposed orientation: direct-reg nt f32x4.
// Normal orientation: two 64-row bounce passes.
__global__ __launch_bounds__(256, 4) void k_decode_sym(const ushort* __restrict__ Hb,
                                                       float* __restrict__ C, int N) {
  __shared__ __align__(16) float ft[64 * 128];   // 32KB bounce

  const int tid = threadIdx.x;
  const int lane = tid & 63;
  const int wv = tid >> 6;
  const int wr = wv >> 1, wc = wv & 1;

  int t = blockIdx.x;
  int bi = (int)((sqrtf(8.f * (float)t + 1.f) - 1.f) * 0.5f);
  while ((bi + 1) * (bi + 2) / 2 <= t) bi++;
  while (bi * (bi + 1) / 2 > t) bi--;
  int bj = t - bi * (bi + 1) / 2;
  const long bm = (long)bi * 128;
  const long bn = (long)bj * 128;

  const int kb = ((lane >> 4) << 4);   // byte offset within 64B k-step

  // A-side rows (output rows) and B-side rows (output cols), clamped:
  // garbage from clamped rows only reaches outputs that are discarded at store.
  long arow[4], brow[4];
#pragma unroll
  for (int mi = 0; mi < 4; mi++) {
    long r = bm + wr * 64 + mi * 16 + (lane & 15);
    arow[mi] = (r < N) ? r : (N - 1);
  }
#pragma unroll
  for (int ni = 0; ni < 4; ni++) {
    long r = bn + wc * 64 + ni * 16 + (lane & 15);
    brow[ni] = (r < N) ? r : (N - 1);
  }

  f32x4 acc[4][4];
#pragma unroll
  for (int i = 0; i < 4; i++)
#pragma unroll
    for (int j = 0; j < 4; j++) acc[i][j] = (f32x4){0.f, 0.f, 0.f, 0.f};

#pragma unroll
  for (int ks = 0; ks < 4; ks++) {
    const int cb = (ks * 64 + kb) >> 1;   // ushort index within row
    short8 af[4], bfr[4];
#pragma unroll
    for (int mi = 0; mi < 4; mi++)
      af[mi] = *reinterpret_cast<const short8*>(&Hb[arow[mi] * 128 + cb]);
#pragma unroll
    for (int ni = 0; ni < 4; ni++)
      bfr[ni] = *reinterpret_cast<const short8*>(&Hb[brow[ni] * 128 + cb]);
#pragma unroll
    for (int mi = 0; mi < 4; mi++)
#pragma unroll
      for (int ni = 0; ni < 4; ni++)
        acc[mi][ni] = __builtin_amdgcn_mfma_f32_16x16x32_bf16(af[mi], bfr[ni], acc[mi][ni], 0, 0, 0);
  }

  // sigmoid once in registers
#pragma unroll
  for (int mi = 0; mi < 4; mi++)
#pragma unroll
    for (int ni = 0; ni < 4; ni++)
#pragma unroll
      for (int j = 0; j < 4; j++)
        acc[mi][ni][j] = __builtin_amdgcn_rcpf(1.f + __expf(-acc[mi][ni][j]));

  // transposed orientation: direct from registers, 16 full 64B lines per instr
  if (bi != bj) {
#pragma unroll
    for (int ni = 0; ni < 4; ni++) {
      long gr = bn + wc * 64 + ni * 16 + (lane & 15);
#pragma unroll
      for (int mi = 0; mi < 4; mi++) {
        long gc = bm + wr * 64 + mi * 16 + ((lane >> 4) << 2);
        if (gr < N && gc < N)
          __builtin_nontemporal_store(acc[mi][ni],
                                      reinterpret_cast<f32x4*>(&C[gr * N + gc]));
      }
    }
  }

  // normal orientation: two 64-row bounce passes through the 32KB tile
#pragma unroll
  for (int pass = 0; pass < 2; pass++) {
    if (wr == pass) {
#pragma unroll
      for (int ni = 0; ni < 4; ni++) {
        int col = wc * 64 + ni * 16 + (lane & 15);
#pragma unroll
        for (int mi = 0; mi < 4; mi++) {
          int rb = mi * 16 + ((lane >> 4) << 2);   // 0..63 within pass
#pragma unroll
          for (int j = 0; j < 4; j++) {
            int row = rb + j;
            int byte = (row << 9) + (col << 2);
            byte ^= ((row & 7) << 4);
            *reinterpret_cast<float*>((char*)ft + byte) = acc[mi][ni][j];
          }
        }
      }
    }
    __syncthreads();
    // coalesced read+store: 64 rows x 512B; 256 thr x 16B = 4KB/iter, 8 iters
#pragma unroll
    for (int it = 0; it < 8; it++) {
      int r = (tid >> 5) + it * 8;
      int ch = tid & 31;
      int byte = (r << 9) + (ch << 4);
      byte ^= ((r & 7) << 4);
      f32x4 v = *reinterpret_cast<const f32x4*>((const char*)ft + byte);
      long gr = bm + pass * 64 + r;
      long gc = bn + ch * 4;
      if (gr < N && gc < N)
        __builtin_nontemporal_store(v, reinterpret_cast<f32x4*>(&C[gr * N + gc]));
    }
    __syncthreads();
  }
}

// ---------------- launch ----------------

extern "C" void kernel_launch(void* const* d_in, const int* in_sizes, int n_in,
                              void* d_out, int out_size, void* d_ws, size_t ws_size,
                              hipStream_t stream) {
  const float* x  = (const float*)d_in[0];
  const int*   ei = (const int*)d_in[1];
  const float* W1 = (const float*)d_in[3];
  const float* b1 = (const float*)d_in[4];
  const float* W2 = (const float*)d_in[5];
  const float* b2 = (const float*)d_in[6];

  const int N   = in_sizes[2];          // 10000
  const int E   = in_sizes[1] / 2;      // 320000
  const int Fin = in_sizes[0] / N;      // 512
  const int F1  = in_sizes[4];          // 256
  const int F2  = in_sizes[6];          // 128

  const int* src = ei;
  const int* dst = ei + E;

  float* ws = (float*)d_ws;
  ushort* w1t      = (ushort*)ws;
  ushort* w2t      = (ushort*)(ws + 65536);
  ushort* xb       = (ushort*)(ws + 81920);
  ushort* h1b      = (ushort*)(ws + 2641920);
  ushort* agg1b    = (ushort*)(ws + 3921920);
  ushort* h2b      = (ushort*)(ws + 5201920);
  ushort* hb       = (ushort*)(ws + 5841920);
  float*  dinv     = ws + 6481920;
  int*    cnt      = (int*)(ws + 6492160);
  int*    cursor   = (int*)(ws + 6502400);
  int*    rowstart = (int*)(ws + 6512640);
  unsigned long long* epack = (unsigned long long*)(ws + 6523136);

  float* out_x1 = (float*)d_out;
  float* out_h  = out_x1 + (long)N * N;

  hipMemsetAsync(cnt, 0, (size_t)N * sizeof(int), stream);
  {
    long xq = (long)N * Fin / 4;
    long tot = xq + (long)Fin * F1 + (long)F1 * F2;
    long thr = (tot > (long)E) ? tot : (long)E;
    k_count_prep<<<(unsigned)((thr + 255) / 256), 256, 0, stream>>>(
        dst, cnt, E, x, xb, xq, W1, w1t, Fin, F1, W2, w2t, F1, F2);
  }
  k_scan<<<1, 1024, 0, stream>>>(cnt, rowstart, cursor, dinv, N, E);

  {
    int gemmRows = (N + 63) / 64;
    int csrRows  = (E + 511) / 512;
    dim3 grid(F1 / 128, gemmRows + csrRows);
    k_gemm1_csr<<<grid, 256, 0, stream>>>(xb, w1t, h1b, N, F1, Fin, F1, gemmRows,
                                          src, dst, dinv, cursor, epack, E);
  }
  k_agg<256, 2, false><<<N, 128, 0, stream>>>(h1b, dinv, rowstart, epack, b1,
                                              agg1b, nullptr, N);

  {
    dim3 grid(F2 / 128, (N + 63) / 64);
    k_gemm_bt<64><<<grid, 256, 0, stream>>>(agg1b, w2t, h2b, N, F2, F1, F2);
  }
  k_agg<128, 1, true><<<N, 64, 0, stream>>>(h2b, dinv, rowstart, epack, b2,
                                            hb, out_h, N);

  // decode: x1 = sigmoid(h @ h^T), symmetric triangular grid, LDS-light
  {
    int NB = (N + 127) / 128;
    int nblk = NB * (NB + 1) / 2;
    k_decode_sym<<<nblk, 256, 0, stream>>>(hb, out_x1, N);
  }
}

// Round 19
// 233.270 us; speedup vs baseline: 2.8547x; 1.0357x over previous
//
#include <hip/hip_runtime.h>
#include <math.h>

#define LEAKY 0.01f

using short8   = __attribute__((ext_vector_type(8))) short;
using f32x4    = __attribute__((ext_vector_type(4))) float;
using ushort4e = __attribute__((ext_vector_type(4))) unsigned short;

__device__ __forceinline__ ushort f2bf(float f) {
  uint u = __float_as_uint(f);
  uint r = (u + 0x7FFFu + ((u >> 16) & 1u)) >> 16;
  return (ushort)r;
}
__device__ __forceinline__ float bf2f(ushort h) {
  uint u = ((uint)h) << 16;
  return __uint_as_float(u);
}

// ---------------- fused: degree count + x/W -> bf16 prep ----------------

__global__ void k_count_prep(const int* __restrict__ dst, int* __restrict__ cnt, int E,
                             const float* __restrict__ X, ushort* __restrict__ Xb, long xq,
                             const float* __restrict__ W1, ushort* __restrict__ Wt1,
                             int K1, int N1,
                             const float* __restrict__ W2, ushort* __restrict__ Wt2,
                             int K2, int N2) {
  long i = (long)blockIdx.x * blockDim.x + threadIdx.x;
  if (i < E) atomicAdd(&cnt[dst[i]], 1);
  if (i < xq) {
    long b = i * 4;
    float4 v = *reinterpret_cast<const float4*>(&X[b]);
    ushort4e u = {f2bf(v.x), f2bf(v.y), f2bf(v.z), f2bf(v.w)};
    *reinterpret_cast<ushort4e*>(&Xb[b]) = u;
  } else {
    long j = i - xq;
    long t1 = (long)K1 * N1;
    if (j < t1) {
      int k = (int)(j / N1), n = (int)(j % N1);
      Wt1[(long)n * K1 + k] = f2bf(W1[j]);
    } else if (j < t1 + (long)K2 * N2) {
      long jj = j - t1;
      int k = (int)(jj / N2), n = (int)(jj % N2);
      Wt2[(long)n * K2 + k] = f2bf(W2[jj]);
    }
  }
}

// single block, 1024 threads; N <= 16384. Also emits dinv = rsqrt(cnt+1).
__global__ void k_scan(const int* __restrict__ cnt, int* __restrict__ rowstart,
                       int* __restrict__ cursor, float* __restrict__ dinv,
                       int N, int Etot) {
  __shared__ int part[1024];
  const int t = threadIdx.x;
  const int CH = 16;
  int base = t * CH;
  int local[CH];
  int s = 0;
#pragma unroll
  for (int i = 0; i < CH; i++) {
    int v = (base + i < N) ? cnt[base + i] : 0;
    if (base + i < N) dinv[base + i] = rsqrtf((float)v + 1.0f);
    local[i] = s;
    s += v;
  }
  part[t] = s;
  __syncthreads();
  for (int off = 1; off < 1024; off <<= 1) {
    int add = (t >= off) ? part[t - off] : 0;
    __syncthreads();
    part[t] += add;
    __syncthreads();
  }
  int excl = (t == 0) ? 0 : part[t - 1];
#pragma unroll
  for (int i = 0; i < CH; i++) {
    if (base + i < N) {
      int rs = excl + local[i];
      rowstart[base + i] = rs;
      cursor[base + i] = rs;
    }
  }
  if (t == 0) rowstart[N] = Etot;
}

// ---------------- gather aggregation: bf16 in/out, packed edge records ----------------
template <int F, int WAVES, bool LAST>
__global__ __launch_bounds__(64 * WAVES) void k_agg(const ushort* __restrict__ hlin,
                                                    const float* __restrict__ dinv,
                                                    const int* __restrict__ rowstart,
                                                    const unsigned long long* __restrict__ epack,
                                                    const float* __restrict__ bias,
                                                    ushort* __restrict__ aggb,
                                                    float* __restrict__ outh, int N) {
  constexpr int FS = F / WAVES;
  const int node = blockIdx.x;
  const int tid = threadIdx.x;
  const int w = tid >> 6;
  const int lane = tid & 63;
  const int f0 = w * FS + lane * 2;
  const float di = dinv[node];

  float acc0, acc1;
  {
    uint v = *reinterpret_cast<const uint*>(&hlin[(long)node * F + f0]);
    float dd = di * di;
    acc0 = bf2f((ushort)(v & 0xffff)) * dd;
    acc1 = bf2f((ushort)(v >> 16)) * dd;
  }
  const int e0 = rowstart[node], e1 = rowstart[node + 1];
  int e = e0;
  for (; e + 7 < e1; e += 8) {
#pragma unroll
    for (int u = 0; u < 8; u++) {
      unsigned long long pk = epack[e + u];
      int s = (int)(unsigned)(pk & 0xffffffffull);
      float nm = __uint_as_float((uint)(pk >> 32));
      uint v = *reinterpret_cast<const uint*>(&hlin[(long)s * F + f0]);
      acc0 += bf2f((ushort)(v & 0xffff)) * nm;
      acc1 += bf2f((ushort)(v >> 16)) * nm;
    }
  }
  for (; e < e1; e++) {
    unsigned long long pk = epack[e];
    int s = (int)(unsigned)(pk & 0xffffffffull);
    float nm = __uint_as_float((uint)(pk >> 32));
    uint v = *reinterpret_cast<const uint*>(&hlin[(long)s * F + f0]);
    acc0 += bf2f((ushort)(v & 0xffff)) * nm;
    acc1 += bf2f((ushort)(v >> 16)) * nm;
  }

  float v0 = acc0 + bias[f0];
  float v1 = acc1 + bias[f0 + 1];
  v0 = (v0 > 0.f) ? v0 : (LEAKY * v0);
  v1 = (v1 > 0.f) ? v1 : (LEAKY * v1);
  uint o = (uint)f2bf(v0) | ((uint)f2bf(v1) << 16);
  *reinterpret_cast<uint*>(&aggb[(long)node * F + f0]) = o;
  if constexpr (LAST) {
    float2 fo = make_float2(v0, v1);
    *reinterpret_cast<float2*>(&outh[(long)node * F + f0]) = fo;
  }
}

// ---------------- layer-1 GEMM fused with CSR fill ----------------
__global__ __launch_bounds__(256) void k_gemm1_csr(
    const ushort* __restrict__ Ab, const ushort* __restrict__ Bb,
    ushort* __restrict__ Cb, int M, int Nc, int K, int ldc, int gemmRows,
    const int* __restrict__ src, const int* __restrict__ dst,
    const float* __restrict__ dinv, int* __restrict__ cursor,
    unsigned long long* __restrict__ epack, int E) {
  constexpr int BM = 64;
  constexpr int MI = BM / 32;
  __shared__ __align__(16) ushort lds[(BM + 128) * 128];

  if (blockIdx.y >= gemmRows) {
    int i = ((blockIdx.y - gemmRows) * 2 + blockIdx.x) * 256 + threadIdx.x;
    if (i < E) {
      int d = dst[i];
      int s = src[i];
      int pos = atomicAdd(&cursor[d], 1);
      float nm = dinv[s] * dinv[d];
      unsigned long long pk = ((unsigned long long)__float_as_uint(nm) << 32) |
                              (unsigned long long)(unsigned)s;
      epack[pos] = pk;
    }
    return;
  }

  ushort* ldsA = lds;
  ushort* ldsB = lds + BM * 128;

  const int tid = threadIdx.x;
  const int lane = tid & 63;
  const int wv = tid >> 6;
  const int wr = wv >> 1, wc = wv & 1;
  const long bm = (long)blockIdx.y * BM;
  const long bn = (long)blockIdx.x * 128;

  f32x4 acc[MI][4];
#pragma unroll
  for (int i = 0; i < MI; i++)
#pragma unroll
    for (int j = 0; j < 4; j++) acc[i][j] = (f32x4){0.f, 0.f, 0.f, 0.f};

  const int kb = ((lane >> 4) << 4);

  for (int k0 = 0; k0 < K; k0 += 128) {
#pragma unroll
    for (int it = 0; it < BM / 16; it++) {
      int off = it * 4096 + tid * 16;
      int row = off >> 8;
      int cb = off & 255;
      long gr = bm + row;
      uint4 v = make_uint4(0u, 0u, 0u, 0u);
      if (gr < M) v = *reinterpret_cast<const uint4*>(&Ab[gr * K + k0 + (cb >> 1)]);
      int sb = (row << 8) | (cb ^ ((row & 7) << 4));
      *reinterpret_cast<uint4*>((char*)ldsA + sb) = v;
    }
#pragma unroll
    for (int it = 0; it < 8; it++) {
      int off = it * 4096 + tid * 16;
      int row = off >> 8;
      int cb = off & 255;
      long gn = bn + row;
      uint4 v = make_uint4(0u, 0u, 0u, 0u);
      if (gn < Nc) v = *reinterpret_cast<const uint4*>(&Bb[gn * K + k0 + (cb >> 1)]);
      int sb = (row << 8) | (cb ^ ((row & 7) << 4));
      *reinterpret_cast<uint4*>((char*)ldsB + sb) = v;
    }
    __syncthreads();

#pragma unroll
    for (int ks = 0; ks < 4; ks++) {
      short8 af[MI], bfr[4];
#pragma unroll
      for (int mi = 0; mi < MI; mi++) {
        int row = wr * (BM / 2) + mi * 16 + (lane & 15);
        int b = ks * 64 + kb;
        int addr = (row << 8) | (b ^ ((row & 7) << 4));
        af[mi] = *reinterpret_cast<const short8*>((const char*)ldsA + addr);
      }
#pragma unroll
      for (int ni = 0; ni < 4; ni++) {
        int row = wc * 64 + ni * 16 + (lane & 15);
        int b = ks * 64 + kb;
        int addr = (row << 8) | (b ^ ((row & 7) << 4));
        bfr[ni] = *reinterpret_cast<const short8*>((const char*)ldsB + addr);
      }
#pragma unroll
      for (int mi = 0; mi < MI; mi++)
#pragma unroll
        for (int ni = 0; ni < 4; ni++)
          acc[mi][ni] = __builtin_amdgcn_mfma_f32_16x16x32_bf16(af[mi], bfr[ni], acc[mi][ni], 0, 0, 0);
    }
    __syncthreads();
  }

#pragma unroll
  for (int ni = 0; ni < 4; ni++) {
    long col = bn + wc * 64 + ni * 16 + (lane & 15);
    if (col >= Nc) continue;
#pragma unroll
    for (int mi = 0; mi < MI; mi++) {
      long rbase2 = bm + wr * (BM / 2) + mi * 16 + ((lane >> 4) << 2);
#pragma unroll
      for (int j = 0; j < 4; j++) {
        long row = rbase2 + j;
        if (row >= M) continue;
        Cb[row * ldc + col] = f2bf(acc[mi][ni][j]);
      }
    }
  }
}

// ---------------- bf16 MFMA GEMM-BT (layer 2), BM=64, bf16 out ----------------
template <int BM>
__global__ __launch_bounds__(256) void k_gemm_bt(const ushort* __restrict__ Ab,
                                                 const ushort* __restrict__ Bb,
                                                 ushort* __restrict__ Cb,
                                                 int M, int N, int K, int ldc) {
  constexpr int MI = BM / 32;
  __shared__ __align__(16) ushort lds[(BM + 128) * 128];
  ushort* ldsA = lds;
  ushort* ldsB = lds + BM * 128;

  const int tid = threadIdx.x;
  const int lane = tid & 63;
  const int wv = tid >> 6;
  const int wr = wv >> 1, wc = wv & 1;
  const long bm = (long)blockIdx.y * BM;
  const long bn = (long)blockIdx.x * 128;

  f32x4 acc[MI][4];
#pragma unroll
  for (int i = 0; i < MI; i++)
#pragma unroll
    for (int j = 0; j < 4; j++) acc[i][j] = (f32x4){0.f, 0.f, 0.f, 0.f};

  const int kb = ((lane >> 4) << 4);

  for (int k0 = 0; k0 < K; k0 += 128) {
#pragma unroll
    for (int it = 0; it < BM / 16; it++) {
      int off = it * 4096 + tid * 16;
      int row = off >> 8;
      int cb = off & 255;
      long gr = bm + row;
      uint4 v = make_uint4(0u, 0u, 0u, 0u);
      if (gr < M) v = *reinterpret_cast<const uint4*>(&Ab[gr * K + k0 + (cb >> 1)]);
      int sb = (row << 8) | (cb ^ ((row & 7) << 4));
      *reinterpret_cast<uint4*>((char*)ldsA + sb) = v;
    }
#pragma unroll
    for (int it = 0; it < 8; it++) {
      int off = it * 4096 + tid * 16;
      int row = off >> 8;
      int cb = off & 255;
      long gn = bn + row;
      uint4 v = make_uint4(0u, 0u, 0u, 0u);
      if (gn < N) v = *reinterpret_cast<const uint4*>(&Bb[gn * K + k0 + (cb >> 1)]);
      int sb = (row << 8) | (cb ^ ((row & 7) << 4));
      *reinterpret_cast<uint4*>((char*)ldsB + sb) = v;
    }
    __syncthreads();

#pragma unroll
    for (int ks = 0; ks < 4; ks++) {
      short8 af[MI], bfr[4];
#pragma unroll
      for (int mi = 0; mi < MI; mi++) {
        int row = wr * (BM / 2) + mi * 16 + (lane & 15);
        int b = ks * 64 + kb;
        int addr = (row << 8) | (b ^ ((row & 7) << 4));
        af[mi] = *reinterpret_cast<const short8*>((const char*)ldsA + addr);
      }
#pragma unroll
      for (int ni = 0; ni < 4; ni++) {
        int row = wc * 64 + ni * 16 + (lane & 15);
        int b = ks * 64 + kb;
        int addr = (row << 8) | (b ^ ((row & 7) << 4));
        bfr[ni] = *reinterpret_cast<const short8*>((const char*)ldsB + addr);
      }
#pragma unroll
      for (int mi = 0; mi < MI; mi++)
#pragma unroll
        for (int ni = 0; ni < 4; ni++)
          acc[mi][ni] = __builtin_amdgcn_mfma_f32_16x16x32_bf16(af[mi], bfr[ni], acc[mi][ni], 0, 0, 0);
    }
    __syncthreads();
  }

#pragma unroll
  for (int ni = 0; ni < 4; ni++) {
    long col = bn + wc * 64 + ni * 16 + (lane & 15);
    if (col >= N) continue;
#pragma unroll
    for (int mi = 0; mi < MI; mi++) {
      long rbase2 = bm + wr * (BM / 2) + mi * 16 + ((lane >> 4) << 2);
#pragma unroll
      for (int j = 0; j < 4; j++) {
        long row = rbase2 + j;
        if (row >= M) continue;
        Cb[row * ldc + col] = f2bf(acc[mi][ni][j]);
      }
    }
  }
}

// ---------------- symmetric decode (R11/R15 form): x1 = sigmoid(H H^T) ----------------
// Triangular grid. Transposed orientation: direct-from-register nt f32x4 (16 full
// 64B lines per instr). Normal orientation: LDS bounce then 512B-contiguous rows.
// Best of 6 measured variants (108us); scattered-512B-run store pattern caps at
// ~3.7 TB/s on this part regardless of nt/plain or store shape.
__global__ __launch_bounds__(256) void k_decode_sym(const ushort* __restrict__ Hb,
                                                    float* __restrict__ C, int N) {
  __shared__ __align__(16) ushort lds[2 * 128 * 128];
  ushort* ldsA = lds;
  ushort* ldsB = lds + 128 * 128;

  const int tid = threadIdx.x;
  const int lane = tid & 63;
  const int wv = tid >> 6;
  const int wr = wv >> 1, wc = wv & 1;

  int t = blockIdx.x;
  int bi = (int)((sqrtf(8.f * (float)t + 1.f) - 1.f) * 0.5f);
  while ((bi + 1) * (bi + 2) / 2 <= t) bi++;
  while (bi * (bi + 1) / 2 > t) bi--;
  int bj = t - bi * (bi + 1) / 2;
  const long bm = (long)bi * 128;
  const long bn = (long)bj * 128;

#pragma unroll
  for (int s = 0; s < 2; s++) {
    long rbase = s ? bn : bm;
    ushort* L = s ? ldsB : ldsA;
#pragma unroll
    for (int it = 0; it < 8; it++) {
      int off = it * 4096 + tid * 16;
      int row = off >> 8;
      int cb = off & 255;
      long grow = rbase + row;
      uint4 v = make_uint4(0u, 0u, 0u, 0u);
      if (grow < N)
        v = *reinterpret_cast<const uint4*>(&Hb[grow * 128 + (cb >> 1)]);
      int sb = (row << 8) | (cb ^ ((row & 7) << 4));
      *reinterpret_cast<uint4*>((char*)L + sb) = v;
    }
  }
  __syncthreads();

  f32x4 acc[4][4];
#pragma unroll
  for (int i = 0; i < 4; i++)
#pragma unroll
    for (int j = 0; j < 4; j++) acc[i][j] = (f32x4){0.f, 0.f, 0.f, 0.f};

  const int kb = ((lane >> 4) << 4);
#pragma unroll
  for (int ks = 0; ks < 4; ks++) {
    short8 af[4], bfr[4];
#pragma unroll
    for (int mi = 0; mi < 4; mi++) {
      int row = wr * 64 + mi * 16 + (lane & 15);
      int b = ks * 64 + kb;
      int addr = (row << 8) | (b ^ ((row & 7) << 4));
      af[mi] = *reinterpret_cast<const short8*>((const char*)ldsA + addr);
    }
#pragma unroll
    for (int ni = 0; ni < 4; ni++) {
      int row = wc * 64 + ni * 16 + (lane & 15);
      int b = ks * 64 + kb;
      int addr = (row << 8) | (b ^ ((row & 7) << 4));
      bfr[ni] = *reinterpret_cast<const short8*>((const char*)ldsB + addr);
    }
#pragma unroll
    for (int mi = 0; mi < 4; mi++)
#pragma unroll
      for (int ni = 0; ni < 4; ni++)
        acc[mi][ni] = __builtin_amdgcn_mfma_f32_16x16x32_bf16(af[mi], bfr[ni], acc[mi][ni], 0, 0, 0);
  }

#pragma unroll
  for (int mi = 0; mi < 4; mi++)
#pragma unroll
    for (int ni = 0; ni < 4; ni++)
#pragma unroll
      for (int j = 0; j < 4; j++)
        acc[mi][ni][j] = __builtin_amdgcn_rcpf(1.f + __expf(-acc[mi][ni][j]));

  if (bi != bj) {
#pragma unroll
    for (int ni = 0; ni < 4; ni++) {
      long gr = bn + wc * 64 + ni * 16 + (lane & 15);
#pragma unroll
      for (int mi = 0; mi < 4; mi++) {
        long gc = bm + wr * 64 + mi * 16 + ((lane >> 4) << 2);
        if (gr < N && gc < N)
          __builtin_nontemporal_store(acc[mi][ni],
                                      reinterpret_cast<f32x4*>(&C[gr * N + gc]));
      }
    }
  }

  __syncthreads();

  float* ft = (float*)lds;
#pragma unroll
  for (int ni = 0; ni < 4; ni++) {
    int col = wc * 64 + ni * 16 + (lane & 15);
#pragma unroll
    for (int mi = 0; mi < 4; mi++) {
      int rb = wr * 64 + mi * 16 + ((lane >> 4) << 2);
#pragma unroll
      for (int j = 0; j < 4; j++) {
        int row = rb + j;
        int byte = (row << 9) + (col << 2);
        byte ^= ((row & 7) << 4);
        *reinterpret_cast<float*>((char*)ft + byte) = acc[mi][ni][j];
      }
    }
  }
  __syncthreads();

#pragma unroll
  for (int it = 0; it < 16; it++) {
    int r = (tid >> 5) + it * 8;
    int ch = tid & 31;
    int byte = (r << 9) + (ch << 4);
    byte ^= ((r & 7) << 4);
    f32x4 v = *reinterpret_cast<const f32x4*>((const char*)ft + byte);
    long gr = bm + r;
    long gc = bn + ch * 4;
    if (gr < N && gc < N)
      __builtin_nontemporal_store(v, reinterpret_cast<f32x4*>(&C[gr * N + gc]));
  }
}

// ---------------- launch ----------------

extern "C" void kernel_launch(void* const* d_in, const int* in_sizes, int n_in,
                              void* d_out, int out_size, void* d_ws, size_t ws_size,
                              hipStream_t stream) {
  const float* x  = (const float*)d_in[0];
  const int*   ei = (const int*)d_in[1];
  const float* W1 = (const float*)d_in[3];
  const float* b1 = (const float*)d_in[4];
  const float* W2 = (const float*)d_in[5];
  const float* b2 = (const float*)d_in[6];

  const int N   = in_sizes[2];          // 10000
  const int E   = in_sizes[1] / 2;      // 320000
  const int Fin = in_sizes[0] / N;      // 512
  const int F1  = in_sizes[4];          // 256
  const int F2  = in_sizes[6];          // 128

  const int* src = ei;
  const int* dst = ei + E;

  float* ws = (float*)d_ws;
  ushort* w1t      = (ushort*)ws;
  ushort* w2t      = (ushort*)(ws + 65536);
  ushort* xb       = (ushort*)(ws + 81920);
  ushort* h1b      = (ushort*)(ws + 2641920);
  ushort* agg1b    = (ushort*)(ws + 3921920);
  ushort* h2b      = (ushort*)(ws + 5201920);
  ushort* hb       = (ushort*)(ws + 5841920);
  float*  dinv     = ws + 6481920;
  int*    cnt      = (int*)(ws + 6492160);
  int*    cursor   = (int*)(ws + 6502400);
  int*    rowstart = (int*)(ws + 6512640);
  unsigned long long* epack = (unsigned long long*)(ws + 6523136);

  float* out_x1 = (float*)d_out;
  float* out_h  = out_x1 + (long)N * N;

  hipMemsetAsync(cnt, 0, (size_t)N * sizeof(int), stream);
  {
    long xq = (long)N * Fin / 4;
    long tot = xq + (long)Fin * F1 + (long)F1 * F2;
    long thr = (tot > (long)E) ? tot : (long)E;
    k_count_prep<<<(unsigned)((thr + 255) / 256), 256, 0, stream>>>(
        dst, cnt, E, x, xb, xq, W1, w1t, Fin, F1, W2, w2t, F1, F2);
  }
  k_scan<<<1, 1024, 0, stream>>>(cnt, rowstart, cursor, dinv, N, E);

  {
    int gemmRows = (N + 63) / 64;
    int csrRows  = (E + 511) / 512;
    dim3 grid(F1 / 128, gemmRows + csrRows);
    k_gemm1_csr<<<grid, 256, 0, stream>>>(xb, w1t, h1b, N, F1, Fin, F1, gemmRows,
                                          src, dst, dinv, cursor, epack, E);
  }
  k_agg<256, 2, false><<<N, 128, 0, stream>>>(h1b, dinv, rowstart, epack, b1,
                                              agg1b, nullptr, N);

  {
    dim3 grid(F2 / 128, (N + 63) / 64);
    k_gemm_bt<64><<<grid, 256, 0, stream>>>(agg1b, w2t, h2b, N, F2, F1, F2);
  }
  k_agg<128, 1, true><<<N, 64, 0, stream>>>(h2b, dinv, rowstart, epack, b2,
                                            hb, out_h, N);

  // decode: x1 = sigmoid(h @ h^T), symmetric triangular grid
  {
    int NB = (N + 127) / 128;
    int nblk = NB * (NB + 1) / 2;
    k_decode_sym<<<nblk, 256, 0, stream>>>(hb, out_x1, N);
  }
}